// Round 5
// baseline (207.743 us; speedup 1.0000x reference)
//
#include <hip/hip_runtime.h>
#include <hip/hip_bf16.h>

namespace {

constexpr int kSeq = 2048;
constexpr int kD   = 64;
constexpr int kBH  = 64;   // B*H
constexpr int kQB  = 256;  // q rows per block (4 waves x 64)
constexpr int kBN  = 64;   // kv rows per tile
constexpr int kNT  = kSeq / kBN;
constexpr int kGrid = kBH * (kSeq / kQB);  // 512 blocks = exactly 2/CU
constexpr int kPs  = 72;   // fallback kernel only

typedef __attribute__((ext_vector_type(8))) short bf16x8;
typedef __attribute__((ext_vector_type(4))) float f32x4;
typedef __attribute__((ext_vector_type(2))) unsigned int u32x2;

__device__ __forceinline__ unsigned short f2bf(float f) {
  unsigned int u = __builtin_bit_cast(unsigned int, f);
  u += 0x7fffu + ((u >> 16) & 1u);   // RNE
  return (unsigned short)(u >> 16);
}

__device__ __forceinline__ unsigned int pkbf(float a, float b) {
#if __has_builtin(__builtin_amdgcn_cvt_pk_bf16_f32)
  typedef __attribute__((ext_vector_type(2))) __bf16 bfv2;
  bfv2 r = __builtin_amdgcn_cvt_pk_bf16_f32(a, b);
  return __builtin_bit_cast(unsigned int, r);
#else
  unsigned int ua = __builtin_bit_cast(unsigned int, a) + 0x8000u;
  unsigned int ub = __builtin_bit_cast(unsigned int, b) + 0x8000u;
  return __builtin_amdgcn_perm(ub, ua, 0x07060302);  // {ub.hi16, ua.hi16}
#endif
}

__device__ __forceinline__ float fexp2(float x) {
#if __has_builtin(__builtin_amdgcn_exp2f)
  return __builtin_amdgcn_exp2f(x);
#else
  return exp2f(x);
#endif
}

// async global->LDS, 16B per lane; LDS dest = wave-uniform base + lane*16
__device__ __forceinline__ void load16(const unsigned short* g, unsigned short* l) {
  __builtin_amdgcn_global_load_lds(
      (const __attribute__((address_space(1))) unsigned int*)g,
      (__attribute__((address_space(3))) unsigned int*)l, 16, 0, 0);
}

// ---------- prepass: K fp32->bf16 copy; V fp32->bf16 transpose [bh][d][s] ----
__global__ __launch_bounds__(256) void prep(
    const float* __restrict__ K, const float* __restrict__ V,
    unsigned short* __restrict__ Kbf, unsigned short* __restrict__ Vt) {
  __shared__ float sTf[kD * 65];
  const int tid = threadIdx.x;
  const int bh = blockIdx.x >> 5;
  const int t0 = (blockIdx.x & 31) * 64;
  const float* Kb = K + ((size_t)bh * kSeq + t0) * kD;
  const float* Vb = V + ((size_t)bh * kSeq + t0) * kD;
  unsigned short* Ko = Kbf + ((size_t)bh * kSeq + t0) * kD;
#pragma unroll
  for (int t = 0; t < 4; ++t) {
    const int idx = tid + t * 256;
    const int row = idx >> 4;         // 0..63 (s)
    const int c4  = (idx & 15) * 4;   // d
    const float4 k4 = *(const float4*)(Kb + row * kD + c4);
    u32x2 kp = {pkbf(k4.x, k4.y), pkbf(k4.z, k4.w)};
    *(u32x2*)(Ko + row * kD + c4) = kp;
    const float4 v4 = *(const float4*)(Vb + row * kD + c4);
    sTf[(c4 + 0) * 65 + row] = v4.x;
    sTf[(c4 + 1) * 65 + row] = v4.y;
    sTf[(c4 + 2) * 65 + row] = v4.z;
    sTf[(c4 + 3) * 65 + row] = v4.w;
  }
  __syncthreads();
  const int d = tid >> 2, q = tid & 3;
  const float* ts = &sTf[d * 65 + q * 16];
  float p[16];
#pragma unroll
  for (int j = 0; j < 16; ++j) p[j] = ts[j];
  uint4 a, b;
  a.x = pkbf(p[0], p[1]);   a.y = pkbf(p[2], p[3]);
  a.z = pkbf(p[4], p[5]);   a.w = pkbf(p[6], p[7]);
  b.x = pkbf(p[8], p[9]);   b.y = pkbf(p[10], p[11]);
  b.z = pkbf(p[12], p[13]); b.w = pkbf(p[14], p[15]);
  unsigned short* vo = Vt + ((size_t)bh * kD + d) * kSeq + t0 + q * 16;
  *(uint4*)(vo)     = a;
  *(uint4*)(vo + 8) = b;
}

// ---- main kernel: 4 waves x 4 m-tiles each (256 q rows/block) ----
// K/V LDS fragment reads are per-wave, so 4 waves x 4 m-tiles cuts LDS
// traffic 29% vs 8 waves x 2 m-tiles at identical MFMA/exp2/HBM work.
// Double-buffered K/V, 1 barrier/tile, grid 512 = exactly 2 blocks/CU.
__global__ __launch_bounds__(256, 2) void fattn4(
    const float* __restrict__ Q, const unsigned short* __restrict__ Kbf,
    const unsigned short* __restrict__ Vt, float* __restrict__ O) {
  __shared__ unsigned short sK[2][kBN * kD];   // [kv][d], XOR-swizzled 16B chunks
  __shared__ unsigned short sV[2][kD * kBN];   // [d][kv], XOR-swizzled 16B chunks
  __shared__ unsigned short sP[4 * 64 * kD];   // per-wave P (64 rows), swizzled

  const int tid  = threadIdx.x;
  const int wave = tid >> 6;      // 0..3
  const int lane = tid & 63;
  const int quad = lane >> 4;
  const int l16  = lane & 15;
  const int swz  = l16 & 7;

  // XCD-aware: 8 heads per XCD slice, 8 q-blocks each (L2 K/V locality)
  const int x  = blockIdx.x & 7;
  const int j  = blockIdx.x >> 3;       // 0..63
  const int bh = x * 8 + (j >> 3);      // 0..63
  const int q0 = (j & 7) * kQB;
  const size_t kb = (size_t)bh * kSeq * kD;

  constexpr float cs = 0.18033688011112042f;  // (1/sqrt(64)) * log2(e)

  // Q B-fragments pre-scaled by cs, FOUR m-tiles per wave:
  // qf[mt][kc]: B[n=l16 (q row)][k=kc*32+quad*8+j], q row = wave*64+mt*16+l16
  bf16x8 qf[4][2];
#pragma unroll
  for (int mt = 0; mt < 4; ++mt) {
    const float* qr =
        Q + kb + (size_t)(q0 + wave * 64 + mt * 16 + l16) * kD + quad * 8;
#pragma unroll
    for (int kc = 0; kc < 2; ++kc)
#pragma unroll
      for (int jj = 0; jj < 8; ++jj)
        qf[mt][kc][jj] = (short)f2bf(qr[kc * 32 + jj] * cs);
  }

  bf16x8 ones;
#pragma unroll
  for (int jj = 0; jj < 8; ++jj) ones[jj] = (short)0x3F80;  // bf16 1.0

  // staging: 512 chunks of 16B per tile array; two K-chunks + two V-chunks
  // per thread. LDS chunk i holds global chunk (i&7)^((i>>3)&7) of row i>>3.
  const int i0 = tid, i1 = tid + 256;
  const int r0 = i0 >> 3, c0 = (i0 & 7) ^ (r0 & 7);
  const int r1 = i1 >> 3, c1 = (i1 & 7) ^ (r1 & 7);
  const unsigned short* kg0 = Kbf + kb + r0 * kD + c0 * 8;
  const unsigned short* kg1 = Kbf + kb + r1 * kD + c1 * 8;
  const unsigned short* vg0 = Vt + kb + r0 * kSeq + c0 * 8;
  const unsigned short* vg1 = Vt + kb + r1 * kSeq + c1 * 8;

  f32x4 o[4][4];
#pragma unroll
  for (int mt = 0; mt < 4; ++mt)
#pragma unroll
    for (int dt = 0; dt < 4; ++dt) o[mt][dt] = (f32x4){0.f, 0.f, 0.f, 0.f};
  f32x4 lacc[4];
#pragma unroll
  for (int mt = 0; mt < 4; ++mt) lacc[mt] = (f32x4){0.f, 0.f, 0.f, 0.f};

  unsigned short* pw0 = &sP[(wave * 64 + l16) * kD];  // + mt*16*kD per m-tile

  // prologue: tile 0 into buffer 0
  load16(kg0, &sK[0][i0 * 8]);
  load16(kg1, &sK[0][i1 * 8]);
  load16(vg0, &sV[0][i0 * 8]);
  load16(vg1, &sV[0][i1 * 8]);

  for (int t = 0; t < kNT; ++t) {
    const int p = t & 1;
    // Single barrier: vmcnt drain publishes loads(t) (in flight for a full
    // tile of compute) and separates iter t-1 reads of buf[p^1] from the
    // writes into it issued below.
    __syncthreads();
    if (t + 1 < kNT) {
      const int pn = p ^ 1;
      const size_t ko = (size_t)(t + 1) * kBN * kD;
      const int vo = (t + 1) * kBN;
      load16(kg0 + ko, &sK[pn][i0 * 8]);
      load16(kg1 + ko, &sK[pn][i1 * 8]);
      load16(vg0 + vo, &sV[pn][i0 * 8]);
      load16(vg1 + vo, &sV[pn][i1 * 8]);
    }
    const unsigned short* sKp = sK[p];
    const unsigned short* sVp = sV[p];

    // ---- S^T = K.Q^T for all 4 m-tiles; each kf feeds 4 MFMAs ----
    // lane holds q-row=l16 (of tile mt), kv = nt*16 + quad*4 + r
    f32x4 s[4][4];
#pragma unroll
    for (int mt = 0; mt < 4; ++mt)
#pragma unroll
      for (int nt = 0; nt < 4; ++nt) s[mt][nt] = (f32x4){0.f, 0.f, 0.f, 0.f};
    __builtin_amdgcn_s_setprio(1);
#pragma unroll
    for (int kc = 0; kc < 2; ++kc)
#pragma unroll
      for (int nt = 0; nt < 4; ++nt) {
        const bf16x8 kf = *(const bf16x8*)&sKp[(nt * 16 + l16) * kD +
                                              (((kc * 4 + quad) ^ swz) * 8)];
#pragma unroll
        for (int mt = 0; mt < 4; ++mt)
          s[mt][nt] =
              __builtin_amdgcn_mfma_f32_16x16x32_bf16(kf, qf[mt][kc], s[mt][nt], 0, 0, 0);
      }
    __builtin_amdgcn_s_setprio(0);

    // ---- p = exp2(s); pack 4 consecutive kv -> one b64 swizzled LDS write ----
#pragma unroll
    for (int mt = 0; mt < 4; ++mt) {
      unsigned short* pw = pw0 + mt * 16 * kD;
#pragma unroll
      for (int nt = 0; nt < 4; ++nt) {
        const int pc = ((nt * 2 + (quad >> 1)) ^ swz) * 8 + (quad & 1) * 4;
        u32x2 pp = {pkbf(fexp2(s[mt][nt][0]), fexp2(s[mt][nt][1])),
                    pkbf(fexp2(s[mt][nt][2]), fexp2(s[mt][nt][3]))};
        *(u32x2*)&pw[pc] = pp;
      }
    }

    // ---- O += P.V for all 4 m-tiles; each vf feeds 4 MFMAs ----
    __builtin_amdgcn_s_setprio(1);
#pragma unroll
    for (int kc = 0; kc < 2; ++kc) {
      const int ac = ((kc * 4 + quad) ^ swz) * 8;
      bf16x8 af[4];
#pragma unroll
      for (int mt = 0; mt < 4; ++mt)
        af[mt] = *(const bf16x8*)&pw0[mt * 16 * kD + ac];
#pragma unroll
      for (int mt = 0; mt < 4; ++mt)
        lacc[mt] = __builtin_amdgcn_mfma_f32_16x16x32_bf16(af[mt], ones, lacc[mt], 0, 0, 0);
#pragma unroll
      for (int dt = 0; dt < 4; ++dt) {
        const bf16x8 vf = *(const bf16x8*)&sVp[(dt * 16 + l16) * kBN + ac];
#pragma unroll
        for (int mt = 0; mt < 4; ++mt)
          o[mt][dt] =
              __builtin_amdgcn_mfma_f32_16x16x32_bf16(af[mt], vf, o[mt][dt], 0, 0, 0);
      }
    }
    __builtin_amdgcn_s_setprio(0);
  }

  // ---- epilogue: rows m = quad*4+r, cols d = dt*16+l16; lacc[r] = rowsum ----
#pragma unroll
  for (int mt = 0; mt < 4; ++mt) {
    float* Ob = O + kb + (size_t)(q0 + wave * 64 + mt * 16) * kD;
#pragma unroll
    for (int r = 0; r < 4; ++r) {
      const float inv = 1.f / lacc[mt][r];
#pragma unroll
      for (int dt = 0; dt < 4; ++dt)
        Ob[(quad * 4 + r) * kD + dt * 16 + l16] = o[mt][dt][r] * inv;
    }
  }
}

// ---------- fallback (round-1-style) if ws too small ----------
__global__ __launch_bounds__(256, 4) void fattn_fb(
    const float* __restrict__ Q, const float* __restrict__ K,
    const float* __restrict__ V, float* __restrict__ O) {
  __shared__ unsigned short sK[kBN * kPs];
  __shared__ unsigned short sV[kD * kPs];
  __shared__ unsigned short sP[4 * 16 * kPs];
  const int tid = threadIdx.x, wave = tid >> 6, lane = tid & 63;
  const int quad = lane >> 4, l16 = lane & 15;
  const int bh = blockIdx.x >> 5, q0 = (blockIdx.x & 31) * 64;
  const float* Qb = Q + (size_t)bh * kSeq * kD;
  const float* Kb = K + (size_t)bh * kSeq * kD;
  const float* Vb = V + (size_t)bh * kSeq * kD;
  bf16x8 qf[2];
  {
    const float* qr = Qb + (size_t)(q0 + wave * 16 + l16) * kD + quad * 8;
#pragma unroll
    for (int kc = 0; kc < 2; ++kc)
#pragma unroll
      for (int jj = 0; jj < 8; ++jj) qf[kc][jj] = (short)f2bf(qr[kc * 32 + jj]);
  }
  f32x4 o[4];
#pragma unroll
  for (int dt = 0; dt < 4; ++dt) o[dt] = (f32x4){0.f, 0.f, 0.f, 0.f};
  float lsum[4] = {0.f, 0.f, 0.f, 0.f};
  constexpr float cs = 0.18033688011112042f;
  unsigned short* pw = &sP[wave * 16 * kPs];
  for (int kv0 = 0; kv0 < kSeq; kv0 += kBN) {
    __syncthreads();
#pragma unroll
    for (int t = 0; t < 4; ++t) {
      const int idx = tid + t * 256;
      const int row = idx >> 4, c4 = (idx & 15) * 4;
      const float4 k4 = *(const float4*)(Kb + (size_t)(kv0 + row) * kD + c4);
      unsigned short* kd = &sK[row * kPs + c4];
      kd[0] = f2bf(k4.x); kd[1] = f2bf(k4.y); kd[2] = f2bf(k4.z); kd[3] = f2bf(k4.w);
      const float4 v4 = *(const float4*)(Vb + (size_t)(kv0 + row) * kD + c4);
      sV[(c4 + 0) * kPs + row] = f2bf(v4.x);
      sV[(c4 + 1) * kPs + row] = f2bf(v4.y);
      sV[(c4 + 2) * kPs + row] = f2bf(v4.z);
      sV[(c4 + 3) * kPs + row] = f2bf(v4.w);
    }
    __syncthreads();
    f32x4 s[4];
#pragma unroll
    for (int nt = 0; nt < 4; ++nt) s[nt] = (f32x4){0.f, 0.f, 0.f, 0.f};
#pragma unroll
    for (int kc = 0; kc < 2; ++kc)
#pragma unroll
      for (int nt = 0; nt < 4; ++nt) {
        const bf16x8 kf = *(const bf16x8*)&sK[(nt * 16 + l16) * kPs + kc * 32 + quad * 8];
        s[nt] = __builtin_amdgcn_mfma_f32_16x16x32_bf16(qf[kc], kf, s[nt], 0, 0, 0);
      }
#pragma unroll
    for (int nt = 0; nt < 4; ++nt)
#pragma unroll
      for (int r = 0; r < 4; ++r) {
        const float p = fexp2(s[nt][r] * cs);
        lsum[r] += p;
        pw[(quad * 4 + r) * kPs + nt * 16 + l16] = f2bf(p);
      }
#pragma unroll
    for (int kc = 0; kc < 2; ++kc) {
      const bf16x8 af = *(const bf16x8*)&pw[l16 * kPs + kc * 32 + quad * 8];
#pragma unroll
      for (int dt = 0; dt < 4; ++dt) {
        const bf16x8 vf = *(const bf16x8*)&sV[(dt * 16 + l16) * kPs + kc * 32 + quad * 8];
        o[dt] = __builtin_amdgcn_mfma_f32_16x16x32_bf16(af, vf, o[dt], 0, 0, 0);
      }
    }
  }
#pragma unroll
  for (int r = 0; r < 4; ++r)
#pragma unroll
    for (int off = 1; off < 16; off <<= 1)
      lsum[r] += __shfl_xor(lsum[r], off, 64);
  float* Ob = O + (size_t)bh * kSeq * kD + (size_t)(q0 + wave * 16) * kD;
#pragma unroll
  for (int r = 0; r < 4; ++r) {
    const float inv = 1.f / lsum[r];
#pragma unroll
    for (int dt = 0; dt < 4; ++dt)
      Ob[(quad * 4 + r) * kD + dt * 16 + l16] = o[dt][r] * inv;
  }
}

}  // namespace

extern "C" void kernel_launch(void* const* d_in, const int* in_sizes, int n_in,
                              void* d_out, int out_size, void* d_ws, size_t ws_size,
                              hipStream_t stream) {
  const float* Q = (const float*)d_in[0];
  const float* K = (const float*)d_in[1];
  const float* V = (const float*)d_in[2];
  float* Oo = (float*)d_out;
  const size_t need = (size_t)2 * kBH * kSeq * kD * sizeof(unsigned short);  // 32 MiB
  if (ws_size >= need) {
    unsigned short* Kbf = (unsigned short*)d_ws;
    unsigned short* Vt  = Kbf + (size_t)kBH * kSeq * kD;
    prep<<<dim3(kBH * (kSeq / 64)), dim3(256), 0, stream>>>(K, V, Kbf, Vt);
    fattn4<<<dim3(kGrid), dim3(256), 0, stream>>>(Q, Kbf, Vt, Oo);
  } else {
    fattn_fb<<<dim3(kBH * (kSeq / 64)), dim3(256), 0, stream>>>(Q, K, V, Oo);
  }
}

// Round 6
// 201.634 us; speedup vs baseline: 1.0303x; 1.0303x over previous
//
#include <hip/hip_runtime.h>
#include <hip/hip_bf16.h>

namespace {

constexpr int kSeq = 2048;
constexpr int kD   = 64;
constexpr int kBH  = 64;   // B*H
constexpr int kQB  = 256;  // q rows per block (8 waves x 32)
constexpr int kBN  = 64;   // kv rows per tile
constexpr int kNT  = kSeq / kBN;
constexpr int kGrid = kBH * (kSeq / kQB);  // 512 blocks = exactly 2/CU
constexpr int kPs  = 72;   // fallback kernel only

typedef __attribute__((ext_vector_type(8))) short bf16x8;
typedef __attribute__((ext_vector_type(4))) float f32x4;
typedef __attribute__((ext_vector_type(2))) unsigned int u32x2;
typedef __attribute__((ext_vector_type(4))) unsigned int u32x4;

__device__ __forceinline__ unsigned short f2bf(float f) {
  unsigned int u = __builtin_bit_cast(unsigned int, f);
  u += 0x7fffu + ((u >> 16) & 1u);   // RNE
  return (unsigned short)(u >> 16);
}

__device__ __forceinline__ unsigned int pkbf(float a, float b) {
#if __has_builtin(__builtin_amdgcn_cvt_pk_bf16_f32)
  typedef __attribute__((ext_vector_type(2))) __bf16 bfv2;
  bfv2 r = __builtin_amdgcn_cvt_pk_bf16_f32(a, b);
  return __builtin_bit_cast(unsigned int, r);
#else
  unsigned int ua = __builtin_bit_cast(unsigned int, a) + 0x8000u;
  unsigned int ub = __builtin_bit_cast(unsigned int, b) + 0x8000u;
  return __builtin_amdgcn_perm(ub, ua, 0x07060302);  // {ub.hi16, ua.hi16}
#endif
}

__device__ __forceinline__ float fexp2(float x) {
#if __has_builtin(__builtin_amdgcn_exp2f)
  return __builtin_amdgcn_exp2f(x);
#else
  return exp2f(x);
#endif
}

// two-register half swap: r[0]={a.lanes0-31, b.lanes0-31}, r[1]={a.hi, b.hi}
__device__ __forceinline__ u32x2 plswap32(unsigned int a, unsigned int b) {
#if __has_builtin(__builtin_amdgcn_permlane32_swap)
  return __builtin_amdgcn_permlane32_swap(a, b, false, false);
#else
  const int lane = threadIdx.x & 63;
  unsigned int sa = __shfl_xor(a, 32, 64), sb = __shfl_xor(b, 32, 64);
  u32x2 r;
  r[0] = (lane < 32) ? a : sb;
  r[1] = (lane < 32) ? sa : b;
  return r;
#endif
}

// row16 interleave: r[0]={a.r0, b.r0, a.r2, b.r2}, r[1]={a.r1, b.r1, a.r3, b.r3}
__device__ __forceinline__ u32x2 plswap16(unsigned int a, unsigned int b) {
#if __has_builtin(__builtin_amdgcn_permlane16_swap)
  return __builtin_amdgcn_permlane16_swap(a, b, false, false);
#else
  const int lane = threadIdx.x & 63;
  unsigned int sa = __shfl_xor(a, 16, 64), sb = __shfl_xor(b, 16, 64);
  const bool even = ((lane >> 4) & 1) == 0;
  u32x2 r;
  r[0] = even ? a : sb;
  r[1] = even ? sa : b;
  return r;
#endif
}

// async global->LDS, 16B per lane; LDS dest = wave-uniform base + lane*16
__device__ __forceinline__ void load16(const unsigned short* g, unsigned short* l) {
  __builtin_amdgcn_global_load_lds(
      (const __attribute__((address_space(1))) unsigned int*)g,
      (__attribute__((address_space(3))) unsigned int*)l, 16, 0, 0);
}

// ---------- prepass: K fp32->bf16 copy; V fp32->bf16 transpose [bh][d][s] ----
__global__ __launch_bounds__(256) void prep(
    const float* __restrict__ K, const float* __restrict__ V,
    unsigned short* __restrict__ Kbf, unsigned short* __restrict__ Vt) {
  __shared__ float sTf[kD * 65];
  const int tid = threadIdx.x;
  const int bh = blockIdx.x >> 5;
  const int t0 = (blockIdx.x & 31) * 64;
  const float* Kb = K + ((size_t)bh * kSeq + t0) * kD;
  const float* Vb = V + ((size_t)bh * kSeq + t0) * kD;
  unsigned short* Ko = Kbf + ((size_t)bh * kSeq + t0) * kD;
#pragma unroll
  for (int t = 0; t < 4; ++t) {
    const int idx = tid + t * 256;
    const int row = idx >> 4;         // 0..63 (s)
    const int c4  = (idx & 15) * 4;   // d
    const float4 k4 = *(const float4*)(Kb + row * kD + c4);
    u32x2 kp = {pkbf(k4.x, k4.y), pkbf(k4.z, k4.w)};
    *(u32x2*)(Ko + row * kD + c4) = kp;
    const float4 v4 = *(const float4*)(Vb + row * kD + c4);
    sTf[(c4 + 0) * 65 + row] = v4.x;
    sTf[(c4 + 1) * 65 + row] = v4.y;
    sTf[(c4 + 2) * 65 + row] = v4.z;
    sTf[(c4 + 3) * 65 + row] = v4.w;
  }
  __syncthreads();
  const int d = tid >> 2, q = tid & 3;
  const float* ts = &sTf[d * 65 + q * 16];
  float p[16];
#pragma unroll
  for (int j = 0; j < 16; ++j) p[j] = ts[j];
  uint4 a, b;
  a.x = pkbf(p[0], p[1]);   a.y = pkbf(p[2], p[3]);
  a.z = pkbf(p[4], p[5]);   a.w = pkbf(p[6], p[7]);
  b.x = pkbf(p[8], p[9]);   b.y = pkbf(p[10], p[11]);
  b.z = pkbf(p[12], p[13]); b.w = pkbf(p[14], p[15]);
  unsigned short* vo = Vt + ((size_t)bh * kD + d) * kSeq + t0 + q * 16;
  *(uint4*)(vo)     = a;
  *(uint4*)(vo + 8) = b;
}

// ---- main kernel: 8 waves x 2 q-tiles (256 q rows/block), in-register P ----
// P never touches LDS: after swapped QK^T, lane(quad,l16) holds
// P[q=l16][kv=nt*16+quad*4+r]; the PV A-fragment P[q=l16][kv=quad*8+jj] is
// produced by {A,B} = permlane16_swap(permlane32_swap(x_nt0, x_nt1)) per u32.
// Removes 8 ds_write + 4 ds_read + lgkm chain per wave-tile; LDS 32 KiB.
__global__ __launch_bounds__(512, 4) void fattn8r(
    const float* __restrict__ Q, const unsigned short* __restrict__ Kbf,
    const unsigned short* __restrict__ Vt, float* __restrict__ O) {
  __shared__ unsigned short sK[2][kBN * kD];   // [kv][d], XOR-swizzled 16B chunks
  __shared__ unsigned short sV[2][kD * kBN];   // [d][kv], XOR-swizzled 16B chunks

  const int tid  = threadIdx.x;
  const int wave = tid >> 6;      // 0..7
  const int lane = tid & 63;
  const int quad = lane >> 4;
  const int l16  = lane & 15;
  const int swz  = l16 & 7;

  // XCD-aware: 8 heads per XCD slice, 8 q-blocks each (L2 K/V locality)
  const int x  = blockIdx.x & 7;
  const int j  = blockIdx.x >> 3;       // 0..63
  const int bh = x * 8 + (j >> 3);      // 0..63
  const int q0 = (j & 7) * kQB;
  const size_t kb = (size_t)bh * kSeq * kD;

  constexpr float cs = 0.18033688011112042f;  // (1/sqrt(64)) * log2(e)

  // Q B-fragments pre-scaled by cs, two m-tiles per wave:
  bf16x8 qf[2][2];
#pragma unroll
  for (int mt = 0; mt < 2; ++mt) {
    const float* qr =
        Q + kb + (size_t)(q0 + wave * 32 + mt * 16 + l16) * kD + quad * 8;
#pragma unroll
    for (int kc = 0; kc < 2; ++kc)
#pragma unroll
      for (int jj = 0; jj < 8; ++jj)
        qf[mt][kc][jj] = (short)f2bf(qr[kc * 32 + jj] * cs);
  }

  bf16x8 ones;
#pragma unroll
  for (int jj = 0; jj < 8; ++jj) ones[jj] = (short)0x3F80;  // bf16 1.0

  // staging: 512 chunks of 16B per tile array; one K-chunk + one V-chunk per
  // thread. LDS chunk i holds global chunk (i&7)^((i>>3)&7) of row i>>3.
  const int r0 = tid >> 3, c0 = (tid & 7) ^ (r0 & 7);
  const unsigned short* kg0 = Kbf + kb + r0 * kD + c0 * 8;
  const unsigned short* vg0 = Vt + kb + r0 * kSeq + c0 * 8;

  f32x4 o[2][4];
#pragma unroll
  for (int mt = 0; mt < 2; ++mt)
#pragma unroll
    for (int dt = 0; dt < 4; ++dt) o[mt][dt] = (f32x4){0.f, 0.f, 0.f, 0.f};
  f32x4 lacc[2] = {(f32x4){0.f, 0.f, 0.f, 0.f}, (f32x4){0.f, 0.f, 0.f, 0.f}};

  // prologue: tile 0 into buffer 0
  load16(kg0, &sK[0][tid * 8]);
  load16(vg0, &sV[0][tid * 8]);

  for (int t = 0; t < kNT; ++t) {
    const int p = t & 1;
    // Single barrier: vmcnt drain publishes loads(t) (in flight for a full
    // tile of compute) and separates iter t-1 reads of buf[p^1] from the
    // writes into it issued below.
    __syncthreads();
    if (t + 1 < kNT) {
      const int pn = p ^ 1;
      const size_t ko = (size_t)(t + 1) * kBN * kD;
      const int vo = (t + 1) * kBN;
      load16(kg0 + ko, &sK[pn][tid * 8]);
      load16(vg0 + vo, &sV[pn][tid * 8]);
    }
    const unsigned short* sKp = sK[p];
    const unsigned short* sVp = sV[p];

    // ---- S^T = K.Q^T for both m-tiles; kf shared ----
    // lane holds q-row=l16 (of tile mt), kv = nt*16 + quad*4 + r
    f32x4 sA[4], sB[4];
#pragma unroll
    for (int nt = 0; nt < 4; ++nt) {
      sA[nt] = (f32x4){0.f, 0.f, 0.f, 0.f};
      sB[nt] = (f32x4){0.f, 0.f, 0.f, 0.f};
    }
    __builtin_amdgcn_s_setprio(1);
#pragma unroll
    for (int kc = 0; kc < 2; ++kc)
#pragma unroll
      for (int nt = 0; nt < 4; ++nt) {
        const bf16x8 kf = *(const bf16x8*)&sKp[(nt * 16 + l16) * kD +
                                              (((kc * 4 + quad) ^ swz) * 8)];
        sA[nt] = __builtin_amdgcn_mfma_f32_16x16x32_bf16(kf, qf[0][kc], sA[nt], 0, 0, 0);
        sB[nt] = __builtin_amdgcn_mfma_f32_16x16x32_bf16(kf, qf[1][kc], sB[nt], 0, 0, 0);
      }
    __builtin_amdgcn_s_setprio(0);

    // ---- p = exp2(s); in-register redistribute to PV A-fragments ----
    // x0 = packed nt=2kc (u32: kv pairs {4q+0,4q+1},{4q+2,4q+3}), x1 = nt=2kc+1
    bf16x8 afA[2], afB[2];
#pragma unroll
    for (int kc = 0; kc < 2; ++kc) {
      u32x2 xa0 = {pkbf(fexp2(sA[2 * kc][0]), fexp2(sA[2 * kc][1])),
                   pkbf(fexp2(sA[2 * kc][2]), fexp2(sA[2 * kc][3]))};
      u32x2 xa1 = {pkbf(fexp2(sA[2 * kc + 1][0]), fexp2(sA[2 * kc + 1][1])),
                   pkbf(fexp2(sA[2 * kc + 1][2]), fexp2(sA[2 * kc + 1][3]))};
      u32x2 wa0 = plswap32(xa0[0], xa1[0]);
      u32x2 za0 = plswap16(wa0[0], wa0[1]);
      u32x2 wa1 = plswap32(xa0[1], xa1[1]);
      u32x2 za1 = plswap16(wa1[0], wa1[1]);
      u32x4 av = {za0[0], za1[0], za0[1], za1[1]};  // {A0,A1,B0,B1}
      afA[kc] = __builtin_bit_cast(bf16x8, av);

      u32x2 xb0 = {pkbf(fexp2(sB[2 * kc][0]), fexp2(sB[2 * kc][1])),
                   pkbf(fexp2(sB[2 * kc][2]), fexp2(sB[2 * kc][3]))};
      u32x2 xb1 = {pkbf(fexp2(sB[2 * kc + 1][0]), fexp2(sB[2 * kc + 1][1])),
                   pkbf(fexp2(sB[2 * kc + 1][2]), fexp2(sB[2 * kc + 1][3]))};
      u32x2 wb0 = plswap32(xb0[0], xb1[0]);
      u32x2 zb0 = plswap16(wb0[0], wb0[1]);
      u32x2 wb1 = plswap32(xb0[1], xb1[1]);
      u32x2 zb1 = plswap16(wb1[0], wb1[1]);
      u32x4 bv = {zb0[0], zb1[0], zb0[1], zb1[1]};
      afB[kc] = __builtin_bit_cast(bf16x8, bv);
    }

    // ---- O += P.V for both m-tiles; vf shared ----
    __builtin_amdgcn_s_setprio(1);
#pragma unroll
    for (int kc = 0; kc < 2; ++kc) {
      const int ac = ((kc * 4 + quad) ^ swz) * 8;
      lacc[0] = __builtin_amdgcn_mfma_f32_16x16x32_bf16(afA[kc], ones, lacc[0], 0, 0, 0);
      lacc[1] = __builtin_amdgcn_mfma_f32_16x16x32_bf16(afB[kc], ones, lacc[1], 0, 0, 0);
#pragma unroll
      for (int dt = 0; dt < 4; ++dt) {
        const bf16x8 vf = *(const bf16x8*)&sVp[(dt * 16 + l16) * kBN + ac];
        o[0][dt] = __builtin_amdgcn_mfma_f32_16x16x32_bf16(afA[kc], vf, o[0][dt], 0, 0, 0);
        o[1][dt] = __builtin_amdgcn_mfma_f32_16x16x32_bf16(afB[kc], vf, o[1][dt], 0, 0, 0);
      }
    }
    __builtin_amdgcn_s_setprio(0);
  }

  // ---- epilogue: rows m = quad*4+r, cols d = dt*16+l16; lacc[r] = rowsum ----
#pragma unroll
  for (int mt = 0; mt < 2; ++mt) {
    float* Ob = O + kb + (size_t)(q0 + wave * 32 + mt * 16) * kD;
#pragma unroll
    for (int r = 0; r < 4; ++r) {
      const float inv = 1.f / lacc[mt][r];
#pragma unroll
      for (int dt = 0; dt < 4; ++dt)
        Ob[(quad * 4 + r) * kD + dt * 16 + l16] = o[mt][dt][r] * inv;
    }
  }
}

// ---------- fallback (round-1-style) if ws too small ----------
__global__ __launch_bounds__(256, 4) void fattn_fb(
    const float* __restrict__ Q, const float* __restrict__ K,
    const float* __restrict__ V, float* __restrict__ O) {
  __shared__ unsigned short sK[kBN * kPs];
  __shared__ unsigned short sV[kD * kPs];
  __shared__ unsigned short sP[4 * 16 * kPs];
  const int tid = threadIdx.x, wave = tid >> 6, lane = tid & 63;
  const int quad = lane >> 4, l16 = lane & 15;
  const int bh = blockIdx.x >> 5, q0 = (blockIdx.x & 31) * 64;
  const float* Qb = Q + (size_t)bh * kSeq * kD;
  const float* Kb = K + (size_t)bh * kSeq * kD;
  const float* Vb = V + (size_t)bh * kSeq * kD;
  bf16x8 qf[2];
  {
    const float* qr = Qb + (size_t)(q0 + wave * 16 + l16) * kD + quad * 8;
#pragma unroll
    for (int kc = 0; kc < 2; ++kc)
#pragma unroll
      for (int jj = 0; jj < 8; ++jj) qf[kc][jj] = (short)f2bf(qr[kc * 32 + jj]);
  }
  f32x4 o[4];
#pragma unroll
  for (int dt = 0; dt < 4; ++dt) o[dt] = (f32x4){0.f, 0.f, 0.f, 0.f};
  float lsum[4] = {0.f, 0.f, 0.f, 0.f};
  constexpr float cs = 0.18033688011112042f;
  unsigned short* pw = &sP[wave * 16 * kPs];
  for (int kv0 = 0; kv0 < kSeq; kv0 += kBN) {
    __syncthreads();
#pragma unroll
    for (int t = 0; t < 4; ++t) {
      const int idx = tid + t * 256;
      const int row = idx >> 4, c4 = (idx & 15) * 4;
      const float4 k4 = *(const float4*)(Kb + (size_t)(kv0 + row) * kD + c4);
      unsigned short* kd = &sK[row * kPs + c4];
      kd[0] = f2bf(k4.x); kd[1] = f2bf(k4.y); kd[2] = f2bf(k4.z); kd[3] = f2bf(k4.w);
      const float4 v4 = *(const float4*)(Vb + (size_t)(kv0 + row) * kD + c4);
      sV[(c4 + 0) * kPs + row] = f2bf(v4.x);
      sV[(c4 + 1) * kPs + row] = f2bf(v4.y);
      sV[(c4 + 2) * kPs + row] = f2bf(v4.z);
      sV[(c4 + 3) * kPs + row] = f2bf(v4.w);
    }
    __syncthreads();
    f32x4 s[4];
#pragma unroll
    for (int nt = 0; nt < 4; ++nt) s[nt] = (f32x4){0.f, 0.f, 0.f, 0.f};
#pragma unroll
    for (int kc = 0; kc < 2; ++kc)
#pragma unroll
      for (int nt = 0; nt < 4; ++nt) {
        const bf16x8 kf = *(const bf16x8*)&sK[(nt * 16 + l16) * kPs + kc * 32 + quad * 8];
        s[nt] = __builtin_amdgcn_mfma_f32_16x16x32_bf16(qf[kc], kf, s[nt], 0, 0, 0);
      }
#pragma unroll
    for (int nt = 0; nt < 4; ++nt)
#pragma unroll
      for (int r = 0; r < 4; ++r) {
        const float p = fexp2(s[nt][r] * cs);
        lsum[r] += p;
        pw[(quad * 4 + r) * kPs + nt * 16 + l16] = f2bf(p);
      }
#pragma unroll
    for (int kc = 0; kc < 2; ++kc) {
      const bf16x8 af = *(const bf16x8*)&pw[l16 * kPs + kc * 32 + quad * 8];
#pragma unroll
      for (int dt = 0; dt < 4; ++dt) {
        const bf16x8 vf = *(const bf16x8*)&sV[(dt * 16 + l16) * kPs + kc * 32 + quad * 8];
        o[dt] = __builtin_amdgcn_mfma_f32_16x16x32_bf16(af, vf, o[dt], 0, 0, 0);
      }
    }
  }
#pragma unroll
  for (int r = 0; r < 4; ++r)
#pragma unroll
    for (int off = 1; off < 16; off <<= 1)
      lsum[r] += __shfl_xor(lsum[r], off, 64);
  float* Ob = O + (size_t)bh * kSeq * kD + (size_t)(q0 + wave * 16) * kD;
#pragma unroll
  for (int r = 0; r < 4; ++r) {
    const float inv = 1.f / lsum[r];
#pragma unroll
    for (int dt = 0; dt < 4; ++dt)
      Ob[(quad * 4 + r) * kD + dt * 16 + l16] = o[dt][r] * inv;
  }
}

}  // namespace

extern "C" void kernel_launch(void* const* d_in, const int* in_sizes, int n_in,
                              void* d_out, int out_size, void* d_ws, size_t ws_size,
                              hipStream_t stream) {
  const float* Q = (const float*)d_in[0];
  const float* K = (const float*)d_in[1];
  const float* V = (const float*)d_in[2];
  float* Oo = (float*)d_out;
  const size_t need = (size_t)2 * kBH * kSeq * kD * sizeof(unsigned short);  // 32 MiB
  if (ws_size >= need) {
    unsigned short* Kbf = (unsigned short*)d_ws;
    unsigned short* Vt  = Kbf + (size_t)kBH * kSeq * kD;
    prep<<<dim3(kBH * (kSeq / 64)), dim3(256), 0, stream>>>(K, V, Kbf, Vt);
    fattn8r<<<dim3(kGrid), dim3(512), 0, stream>>>(Q, Kbf, Vt, Oo);
  } else {
    fattn_fb<<<dim3(kBH * (kSeq / 64)), dim3(256), 0, stream>>>(Q, K, V, Oo);
  }
}